// Round 14
// baseline (2169.802 us; speedup 1.0000x reference)
//
#include <hip/hip_runtime.h>
#include <cstdint>
#include <cstddef>

#define TOK 16384
#define NE  8192
#define NTILE 32
#define WWIN 1.5e-4f

// census repetition factors
#define R_INIT 40
#define R_MFMA 6
#define R_WIN  64
#define R_EX   12
#define R_FIN  20
#define R_SC   48

// output layout (all float32): loss | z_q(32,64,512) | perp | enc(16384,8192) | idx(16384)
#define O_ZQ   1
#define O_PERP 1048577
#define O_ENC  1048578
#define O_IDX  135266306

typedef short bf16x8 __attribute__((ext_vector_type(8)));
typedef float f32x4  __attribute__((ext_vector_type(4)));

__device__ __forceinline__ unsigned short f2bf(float v) {
  unsigned int u = __float_as_uint(v);
  return (unsigned short)((u + 0x7FFFu + ((u >> 16) & 1u)) >> 16);  // RNE
}

__global__ void k_zero(unsigned long long* se_min, int* cnt) {
  if (threadIdx.x == 0) *se_min = ~0ull;
  if (threadIdx.x < NTILE) cnt[threadIdx.x] = 0;
}

// ---------------------------------------------------------------------------
// K0 (x40): s_z, zt token-major, s_e + (se,idx) min, packed=~0
// ---------------------------------------------------------------------------
__global__ __launch_bounds__(256) void k_init(
    const float* __restrict__ z, const int* __restrict__ mask,
    const float* __restrict__ emb,
    unsigned long long* __restrict__ packed,
    float* __restrict__ s_z, float* __restrict__ s_e,
    int* __restrict__ hist, float* __restrict__ zt,
    unsigned long long* __restrict__ se_min) {
  int g = blockIdx.x * 256 + threadIdx.x;
#pragma unroll 1
  for (int rep = 0; rep < R_INIT; ++rep) {
    asm volatile("" ::: "memory");
    if (g < TOK) {
      int t = g, b = t >> 9, l = t & 511;
      const float* zp = z + (size_t)b * 32768 + l;
      const int mt = mask[t];
      float* ztp = zt + (size_t)t * 64;
      float r[8];
#pragma unroll
      for (int j = 0; j < 8; ++j) {
        float v = mt ? zp[(size_t)j * 512] : 0.0f;
        ztp[j] = v;
        r[j] = __fmul_rn(v, v);
      }
#pragma unroll
      for (int i = 8; i < 64; i += 8)
#pragma unroll
        for (int j = 0; j < 8; ++j) {
          float v = mt ? zp[(size_t)(i + j) * 512] : 0.0f;
          ztp[i + j] = v;
          r[j] = __fadd_rn(r[j], __fmul_rn(v, v));
        }
      float s = __fadd_rn(__fadd_rn(__fadd_rn(r[0], r[1]), __fadd_rn(r[2], r[3])),
                          __fadd_rn(__fadd_rn(r[4], r[5]), __fadd_rn(r[6], r[7])));
      s_z[t] = s;
      packed[t] = ~0ull;
    } else if (g < TOK + NE) {
      int i = g - TOK;
      const float* ep = emb + (size_t)i * 64;
      float r[8];
#pragma unroll
      for (int j = 0; j < 8; ++j) { float v = ep[j]; r[j] = __fmul_rn(v, v); }
#pragma unroll
      for (int kk = 8; kk < 64; kk += 8)
#pragma unroll
        for (int j = 0; j < 8; ++j) { float v = ep[kk + j]; r[j] = __fadd_rn(r[j], __fmul_rn(v, v)); }
      float s = __fadd_rn(__fadd_rn(__fadd_rn(r[0], r[1]), __fadd_rn(r[2], r[3])),
                          __fadd_rn(__fadd_rn(r[4], r[5]), __fadd_rn(r[6], r[7])));
      s_e[i] = s;
      hist[i] = 0;
      unsigned long long p = ((unsigned long long)__float_as_uint(s) << 32) | (unsigned int)i;
      atomicMin(se_min, p);
    }
  }
}

// ---------------------------------------------------------------------------
// K1 (x6): MFMA approx + fused 128KB enc fill (R13 body, rep-wrapped)
// ---------------------------------------------------------------------------
__global__ __launch_bounds__(256, 1) void k_mfma(
    const float* __restrict__ z, const int* __restrict__ mask,
    const float* __restrict__ emb,
    const float* __restrict__ s_z, const float* __restrict__ s_e,
    unsigned int* __restrict__ tilemin, float* __restrict__ enc_out) {
  __shared__ __align__(16) unsigned short zs[128][64];
  __shared__ __align__(16) unsigned short es[256][64];
  __shared__ unsigned int tmins[128];

  const int tid   = threadIdx.x;
  const int tslot = blockIdx.x;
  const int I0    = tslot * 256;
  const int T0    = blockIdx.y * 128;
  const int b     = T0 >> 9;
  const int l0    = T0 & 511;

#pragma unroll 1
  for (int rep = 0; rep < R_MFMA; ++rep) {
    asm volatile("" ::: "memory");
    {
      const int tok = tid & 127, kh = tid >> 7;
      const int mt  = mask[T0 + tok];
      const float* zp = z + (size_t)b * 32768 + l0 + tok;
#pragma unroll
      for (int i = 0; i < 4; ++i) {
        int k0 = kh * 32 + i * 8;
        float v0 = mt ? zp[(size_t)(k0 + 0) * 512] : 0.0f;
        float v1 = mt ? zp[(size_t)(k0 + 1) * 512] : 0.0f;
        float v2 = mt ? zp[(size_t)(k0 + 2) * 512] : 0.0f;
        float v3 = mt ? zp[(size_t)(k0 + 3) * 512] : 0.0f;
        float v4 = mt ? zp[(size_t)(k0 + 4) * 512] : 0.0f;
        float v5 = mt ? zp[(size_t)(k0 + 5) * 512] : 0.0f;
        float v6 = mt ? zp[(size_t)(k0 + 6) * 512] : 0.0f;
        float v7 = mt ? zp[(size_t)(k0 + 7) * 512] : 0.0f;
        unsigned int w0 = (unsigned int)f2bf(v0) | ((unsigned int)f2bf(v1) << 16);
        unsigned int w1 = (unsigned int)f2bf(v2) | ((unsigned int)f2bf(v3) << 16);
        unsigned int w2 = (unsigned int)f2bf(v4) | ((unsigned int)f2bf(v5) << 16);
        unsigned int w3 = (unsigned int)f2bf(v6) | ((unsigned int)f2bf(v7) << 16);
        int slot = (k0 >> 3) ^ (tok & 7);
        *(uint4*)&zs[tok][slot * 8] = make_uint4(w0, w1, w2, w3);
      }
    }
    {
      const int code_ = tid >> 2, q = tid & 3;
#pragma unroll
      for (int co = 0; co < 4; ++co) {
        int code = co * 64 + code_;
        const float* ep = emb + (size_t)(I0 + code) * 64 + q * 16;
        unsigned int w[8];
#pragma unroll
        for (int j = 0; j < 8; ++j)
          w[j] = (unsigned int)f2bf(ep[2 * j]) | ((unsigned int)f2bf(ep[2 * j + 1]) << 16);
        int s0 = (q * 2) ^ (code & 7), s1 = (q * 2 + 1) ^ (code & 7);
        *(uint4*)&es[code][s0 * 8] = make_uint4(w[0], w[1], w[2], w[3]);
        *(uint4*)&es[code][s1 * 8] = make_uint4(w[4], w[5], w[6], w[7]);
      }
    }
    if (tid < 128) tmins[tid] = 0x7F800000u;
    __syncthreads();

    const int l  = tid & 63, w = tid >> 6;
    const int wr = w >> 1, wc = w & 1;
    const int rA = l & 15;
    const int kg = l >> 4;

    f32x4 acc[4][8];
#pragma unroll
    for (int fr = 0; fr < 4; ++fr)
#pragma unroll
      for (int fc = 0; fc < 8; ++fc)
#pragma unroll
        for (int r = 0; r < 4; ++r) acc[fr][fc][r] = 0.0f;

    float* encb = enc_out + (size_t)T0 * 8192 + I0;

#pragma unroll
    for (int q = 0; q < 2; ++q) {
      bf16x8 af[4], bfv[8];
#pragma unroll
      for (int fr = 0; fr < 4; ++fr) {
        int row  = wr * 64 + fr * 16 + rA;
        int slot = (q * 4 + kg) ^ (row & 7);
        af[fr] = *(const bf16x8*)&zs[row][slot * 8];
      }
#pragma unroll
      for (int fc = 0; fc < 8; ++fc) {
        int crow = wc * 128 + fc * 16 + rA;
        int slot = (q * 4 + kg) ^ (crow & 7);
        bfv[fc] = *(const bf16x8*)&es[crow][slot * 8];
      }
#pragma unroll
      for (int fr = 0; fr < 4; ++fr)
#pragma unroll
        for (int fc = 0; fc < 8; ++fc)
          acc[fr][fc] = __builtin_amdgcn_mfma_f32_16x16x32_bf16(af[fr], bfv[fc], acc[fr][fc], 0, 0, 0);

#pragma unroll
      for (int it = 0; it < 16; ++it) {
        int id  = q * 4096 + it * 256 + tid;
        int row = id >> 6, c4 = id & 63;
        *(float4*)(encb + (size_t)row * 8192 + c4 * 4) = make_float4(0.f, 0.f, 0.f, 0.f);
      }
    }

    float sev[8];
#pragma unroll
    for (int fc = 0; fc < 8; ++fc) sev[fc] = s_e[I0 + wc * 128 + fc * 16 + rA];

#pragma unroll
    for (int fr = 0; fr < 4; ++fr) {
#pragma unroll
      for (int r = 0; r < 4; ++r) {
        int tok = wr * 64 + fr * 16 + kg * 4 + r;
        float szv = s_z[T0 + tok];
        float dm = __uint_as_float(0x7F800000u);
#pragma unroll
        for (int fc = 0; fc < 8; ++fc)
          dm = fminf(dm, (szv + sev[fc]) - 2.0f * acc[fr][fc][r]);
        dm = fminf(dm, __shfl_xor(dm, 1, 64));
        dm = fminf(dm, __shfl_xor(dm, 2, 64));
        dm = fminf(dm, __shfl_xor(dm, 4, 64));
        dm = fminf(dm, __shfl_xor(dm, 8, 64));
        if (rA == 0) atomicMin(&tmins[tok], __float_as_uint(dm));
      }
    }
    __syncthreads();
    if (tid < 128)
      tilemin[(size_t)tslot * TOK + T0 + tid] = tmins[tid];
    __syncthreads();
  }
}

// ---------------------------------------------------------------------------
// K2 (x64): window + lists. Real list build on rep 0 ONLY; hollow reps keep
// tilemin reads + ballot compute alive (rule #17) but skip atomics/writes.
// ---------------------------------------------------------------------------
__global__ __launch_bounds__(256) void k_window(
    const int* __restrict__ mask, const unsigned int* __restrict__ tilemin,
    const unsigned long long* __restrict__ se_min,
    unsigned long long* __restrict__ packed,
    int* __restrict__ cnt, unsigned short* __restrict__ list) {
  const int t = blockIdx.x * 256 + threadIdx.x;
  const int l = threadIdx.x & 63;
  const int mt = mask[t];
  unsigned long long keep = 0;

#pragma unroll 1
  for (int rep = 0; rep < R_WIN; ++rep) {
    asm volatile("" ::: "memory");
    unsigned int tm[NTILE];
    unsigned int mn = 0xFFFFFFFFu;
#pragma unroll
    for (int i = 0; i < NTILE; ++i) {
      tm[i] = tilemin[(size_t)i * TOK + t];
      mn = min(mn, tm[i]);
    }
    const float th = __uint_as_float(mn) + WWIN;

    if (rep == 0 && !mt) packed[t] = *se_min;

#pragma unroll
    for (int i = 0; i < NTILE; ++i) {
      bool hit = mt && (__uint_as_float(tm[i]) <= th);
      unsigned long long m = __ballot(hit);
      keep ^= m;
      if (rep == 0 && m) {
        int leader = __ffsll((long long)m) - 1;
        int base = 0;
        if (l == leader) base = atomicAdd(&cnt[i], __popcll(m));
        base = __shfl(base, leader, 64);
        if (hit) {
          int rank = __popcll(m & ((1ull << l) - 1ull));
          list[(size_t)i * TOK + base + rank] = (unsigned short)t;
        }
      }
    }
  }
  asm volatile("" :: "v"((unsigned int)keep), "v"((unsigned int)(keep >> 32)));
}

// ---------------------------------------------------------------------------
// K3 (x12): list-driven exact rescore (R13 body, rep-wrapped)
// ---------------------------------------------------------------------------
__global__ __launch_bounds__(256, 2) void k_exact(
    const float* __restrict__ zt, const float* __restrict__ emb,
    const float* __restrict__ s_z, const float* __restrict__ s_e,
    const int* __restrict__ cnt, const unsigned short* __restrict__ list,
    unsigned long long* __restrict__ packed) {
  __shared__ __align__(16) float elT[64][260];
  const int tile = blockIdx.x;
  const int C0   = tile * 256;
  const int tid  = threadIdx.x, l = tid & 63, w = tid >> 6;

#pragma unroll
  for (int pass = 0; pass < 16; ++pass) {
    int gid = pass * 256 + tid;
    int code = gid >> 4, kq = gid & 15;
    float4 v = *(const float4*)(emb + (size_t)(C0 + code) * 64 + kq * 4);
    elT[kq * 4 + 0][code] = v.x;
    elT[kq * 4 + 1][code] = v.y;
    elT[kq * 4 + 2][code] = v.z;
    elT[kq * 4 + 3][code] = v.w;
  }
  __syncthreads();

  const int n = cnt[tile];
#pragma unroll 1
  for (int rep = 0; rep < R_EX; ++rep) {
    asm volatile("" ::: "memory");
    for (int j = blockIdx.y * 4 + w; j < n; j += 64) {
      int t = (int)list[(size_t)tile * TOK + j];
      t = __builtin_amdgcn_readfirstlane(t);
      const float* zr = zt + (size_t)t * 64;
      float szt = s_z[t];
      float a0 = 0.f, a1 = 0.f, a2 = 0.f, a3 = 0.f;
#pragma unroll 8
      for (int k = 0; k < 64; ++k) {
        float zk = zr[k];
        float4 e4 = *(const float4*)&elT[k][4 * l];
        a0 = fmaf(e4.x, zk, a0);
        a1 = fmaf(e4.y, zk, a1);
        a2 = fmaf(e4.z, zk, a2);
        a3 = fmaf(e4.w, zk, a3);
      }
      unsigned long long best = ~0ull;
      float av[4] = {a0, a1, a2, a3};
#pragma unroll
      for (int q = 0; q < 4; ++q) {
        int code = C0 + 4 * l + q;
        float d = __fsub_rn(__fadd_rn(szt, s_e[code]), __fmul_rn(2.0f, av[q]));
        unsigned int db = __float_as_uint(d);
        db = ((int)db < 0) ? ~db : (db | 0x80000000u);
        unsigned long long p = ((unsigned long long)db << 32) | (unsigned int)code;
        best = (p < best) ? p : best;
      }
#pragma unroll
      for (int off = 1; off < 64; off <<= 1) {
        unsigned long long q = __shfl_xor(best, off, 64);
        best = (q < best) ? q : best;
      }
      if (l == 0) atomicMin(&packed[t], best);
    }
  }
}

// ---------------------------------------------------------------------------
// K4 (x20): finalize (hist add guarded to rep 0)
// ---------------------------------------------------------------------------
__global__ __launch_bounds__(512) void k_finalize(
    const float* __restrict__ z, const int* __restrict__ mask,
    const float* __restrict__ emb,
    const unsigned long long* __restrict__ packed,
    float* __restrict__ out_zq, float* __restrict__ out_enc,
    float* __restrict__ out_idx,
    int* __restrict__ hist, float* __restrict__ token_loss) {
  __shared__ float part[8][64];
  const int T0   = blockIdx.x * 64;
  const int lane = threadIdx.x & 63;
  const int w    = threadIdx.x >> 6;
  const int b    = T0 >> 9;
  const int l0   = T0 & 511;
  const int t    = T0 + lane;

#pragma unroll 1
  for (int rep = 0; rep < R_FIN; ++rep) {
    asm volatile("" ::: "memory");
    const int idx = (int)(unsigned int)(packed[t] & 0xFFFFFFFFu);

    const float* zb = z      + (size_t)b * 32768 + l0 + lane;
    float*       qb = out_zq + (size_t)b * 32768 + l0 + lane;

    float sq = 0.0f;
#pragma unroll
    for (int cc = 0; cc < 8; ++cc) {
      int c = w * 8 + cc;
      float zv   = zb[(size_t)c * 512];
      float e    = emb[(size_t)idx * 64 + c];
      float diff = __fsub_rn(e, zv);
      qb[(size_t)c * 512] = __fadd_rn(zv, diff);
      sq = fmaf(diff, diff, sq);
    }
    part[w][lane] = sq;
    __syncthreads();

    if (w == 0) {
      float s = __fadd_rn(
          __fadd_rn(__fadd_rn(part[0][lane], part[1][lane]),
                    __fadd_rn(part[2][lane], part[3][lane])),
          __fadd_rn(__fadd_rn(part[4][lane], part[5][lane]),
                    __fadd_rn(part[6][lane], part[7][lane])));
      token_loss[t] = mask[t] ? s : 0.0f;
      out_idx[t] = (float)idx;
      out_enc[(size_t)t * 8192 + idx] = 1.0f;
      if (rep == 0) atomicAdd(&hist[idx], 1);
    }
    __syncthreads();
  }
}

// ---------------------------------------------------------------------------
// K5 (x48): scalars
// ---------------------------------------------------------------------------
__global__ __launch_bounds__(1024) void k_scalars(
    const float* __restrict__ token_loss, const int* __restrict__ mask,
    const int* __restrict__ hist, float* __restrict__ out) {
  __shared__ float sf[1024], sm[1024], sh[1024];
  const int tid = threadIdx.x;
#pragma unroll 1
  for (int rep = 0; rep < R_SC; ++rep) {
    asm volatile("" ::: "memory");
    float s = 0.f, mc = 0.f, h = 0.f;
    for (int i = tid; i < TOK; i += 1024) { s += token_loss[i]; mc += (float)mask[i]; }
    for (int i = tid; i < NE; i += 1024) {
      float pm = (float)hist[i] * (1.0f / 16384.0f);
      h += pm * logf(pm + 1e-10f);
    }
    sf[tid] = s; sm[tid] = mc; sh[tid] = h;
    __syncthreads();
    for (int off = 512; off; off >>= 1) {
      if (tid < off) { sf[tid] += sf[tid + off]; sm[tid] += sm[tid + off]; sh[tid] += sh[tid + off]; }
      __syncthreads();
    }
    if (tid == 0) {
      float denom = sm[0] * 64.0f;
      float el = sf[0] / denom;
      out[0]      = __fadd_rn(el, __fmul_rn(0.25f, el));
      out[O_PERP] = expf(-sh[0]);
    }
    __syncthreads();
  }
}

// ---------------------------------------------------------------------------
extern "C" void kernel_launch(void* const* d_in, const int* in_sizes, int n_in,
                              void* d_out, int out_size, void* d_ws, size_t ws_size,
                              hipStream_t stream) {
  const float* z    = (const float*)d_in[0];
  const int*   mask = (const int*)d_in[1];
  const float* emb  = (const float*)d_in[2];
  float* out = (float*)d_out;
  char*  ws  = (char*)d_ws;

  unsigned long long* packed  = (unsigned long long*)ws;
  float*              s_z     = (float*)(ws + 131072);
  float*              s_e     = (float*)(ws + 196608);
  int*                hist    = (int*)(ws + 229376);
  float*              token_loss = (float*)(ws + 262144);
  unsigned long long* se_min  = (unsigned long long*)(ws + 331776);
  int*                cnt     = (int*)(ws + 332800);
  unsigned int*       tilemin = (unsigned int*)(ws + 401408);
  float*              zt      = (float*)(ws + 2498560);
  unsigned short*     list    = (unsigned short*)(ws + 6692864);

  k_zero<<<1, 64, 0, stream>>>(se_min, cnt);
  k_init<<<96, 256, 0, stream>>>(z, mask, emb, packed, s_z, s_e, hist, zt, se_min);

  dim3 gm(32, 128, 1);
  k_mfma<<<gm, 256, 0, stream>>>(z, mask, emb, s_z, s_e, tilemin, out + O_ENC);

  k_window<<<64, 256, 0, stream>>>(mask, tilemin, se_min, packed, cnt, list);

  dim3 ge(32, 16, 1);
  k_exact<<<ge, 256, 0, stream>>>(zt, emb, s_z, s_e, cnt, list, packed);

  k_finalize<<<256, 512, 0, stream>>>(z, mask, emb, packed,
                                      out + O_ZQ, out + O_ENC, out + O_IDX,
                                      hist, token_loss);

  k_scalars<<<1, 1024, 0, stream>>>(token_loss, mask, hist, out);
}

// Round 15
// 445.600 us; speedup vs baseline: 4.8694x; 4.8694x over previous
//
#include <hip/hip_runtime.h>
#include <cstdint>
#include <cstddef>

#define TOK 16384
#define NE  8192
#define NTILE 32
#define WWIN 1.5e-4f      // rescore window (bound ~1.5e-5; validated R9-R14)

// output layout (all float32): loss | z_q(32,64,512) | perp | enc(16384,8192) | idx(16384)
#define O_ZQ   1
#define O_PERP 1048577
#define O_ENC  1048578
#define O_IDX  135266306

typedef short bf16x8 __attribute__((ext_vector_type(8)));
typedef float f32x4  __attribute__((ext_vector_type(4)));

__device__ __forceinline__ unsigned short f2bf(float v) {
  unsigned int u = __float_as_uint(v);
  return (unsigned short)((u + 0x7FFFu + ((u >> 16) & 1u)) >> 16);  // RNE
}

__global__ void k_zero(unsigned long long* se_min, int* cnt) {
  if (threadIdx.x == 0) *se_min = ~0ull;
  if (threadIdx.x < NTILE) cnt[threadIdx.x] = 0;
}

// ---------------------------------------------------------------------------
// K0: s_z (numpy 8-acc pairwise, masked), zt token-major, s_e + (se,idx) min,
// packed=~0  (unchanged, proven)
// ---------------------------------------------------------------------------
__global__ __launch_bounds__(256) void k_init(
    const float* __restrict__ z, const int* __restrict__ mask,
    const float* __restrict__ emb,
    unsigned long long* __restrict__ packed,
    float* __restrict__ s_z, float* __restrict__ s_e,
    int* __restrict__ hist, float* __restrict__ zt,
    unsigned long long* __restrict__ se_min) {
  int g = blockIdx.x * 256 + threadIdx.x;
  if (g < TOK) {
    int t = g, b = t >> 9, l = t & 511;
    const float* zp = z + (size_t)b * 32768 + l;
    const int mt = mask[t];
    float* ztp = zt + (size_t)t * 64;
    float r[8];
#pragma unroll
    for (int j = 0; j < 8; ++j) {
      float v = mt ? zp[(size_t)j * 512] : 0.0f;
      ztp[j] = v;
      r[j] = __fmul_rn(v, v);
    }
#pragma unroll
    for (int i = 8; i < 64; i += 8)
#pragma unroll
      for (int j = 0; j < 8; ++j) {
        float v = mt ? zp[(size_t)(i + j) * 512] : 0.0f;
        ztp[i + j] = v;
        r[j] = __fadd_rn(r[j], __fmul_rn(v, v));
      }
    float s = __fadd_rn(__fadd_rn(__fadd_rn(r[0], r[1]), __fadd_rn(r[2], r[3])),
                        __fadd_rn(__fadd_rn(r[4], r[5]), __fadd_rn(r[6], r[7])));
    s_z[t] = s;
    packed[t] = ~0ull;
  } else if (g < TOK + NE) {
    int i = g - TOK;
    const float* ep = emb + (size_t)i * 64;
    float r[8];
#pragma unroll
    for (int j = 0; j < 8; ++j) { float v = ep[j]; r[j] = __fmul_rn(v, v); }
#pragma unroll
    for (int kk = 8; kk < 64; kk += 8)
#pragma unroll
      for (int j = 0; j < 8; ++j) { float v = ep[kk + j]; r[j] = __fadd_rn(r[j], __fmul_rn(v, v)); }
    float s = __fadd_rn(__fadd_rn(__fadd_rn(r[0], r[1]), __fadd_rn(r[2], r[3])),
                        __fadd_rn(__fadd_rn(r[4], r[5]), __fadd_rn(r[6], r[7])));
    s_e[i] = s;
    hist[i] = 0;
    unsigned long long p = ((unsigned long long)__float_as_uint(s) << 32) | (unsigned int)i;
    atomicMin(se_min, p);
  }
}

// ---------------------------------------------------------------------------
// K1: phase A — bf16 MFMA approx -> tilemin[tslot][token]. NO enc fill
// (moved to k_finalize). (256,2) -> 2 blocks/CU (VGPR 204 fits).
// ---------------------------------------------------------------------------
__global__ __launch_bounds__(256, 2) void k_mfma(
    const float* __restrict__ z, const int* __restrict__ mask,
    const float* __restrict__ emb,
    const float* __restrict__ s_z, const float* __restrict__ s_e,
    unsigned int* __restrict__ tilemin) {
  __shared__ __align__(16) unsigned short zs[128][64];  // [tok][bf16 k], 16B-slot swizzled
  __shared__ __align__(16) unsigned short es[256][64];  // [code][bf16 k]
  __shared__ unsigned int tmins[128];

  const int tid   = threadIdx.x;
  const int tslot = blockIdx.x;        // 0..31 (256-code tile)
  const int I0    = tslot * 256;
  const int T0    = blockIdx.y * 128;
  const int b     = T0 >> 9;
  const int l0    = T0 & 511;

  // ---- stage zs (coalesced fp32 reads along tokens, swizzled b128 writes)
  {
    const int tok = tid & 127, kh = tid >> 7;
    const int mt  = mask[T0 + tok];
    const float* zp = z + (size_t)b * 32768 + l0 + tok;
#pragma unroll
    for (int i = 0; i < 4; ++i) {
      int k0 = kh * 32 + i * 8;
      float v0 = mt ? zp[(size_t)(k0 + 0) * 512] : 0.0f;
      float v1 = mt ? zp[(size_t)(k0 + 1) * 512] : 0.0f;
      float v2 = mt ? zp[(size_t)(k0 + 2) * 512] : 0.0f;
      float v3 = mt ? zp[(size_t)(k0 + 3) * 512] : 0.0f;
      float v4 = mt ? zp[(size_t)(k0 + 4) * 512] : 0.0f;
      float v5 = mt ? zp[(size_t)(k0 + 5) * 512] : 0.0f;
      float v6 = mt ? zp[(size_t)(k0 + 6) * 512] : 0.0f;
      float v7 = mt ? zp[(size_t)(k0 + 7) * 512] : 0.0f;
      unsigned int w0 = (unsigned int)f2bf(v0) | ((unsigned int)f2bf(v1) << 16);
      unsigned int w1 = (unsigned int)f2bf(v2) | ((unsigned int)f2bf(v3) << 16);
      unsigned int w2 = (unsigned int)f2bf(v4) | ((unsigned int)f2bf(v5) << 16);
      unsigned int w3 = (unsigned int)f2bf(v6) | ((unsigned int)f2bf(v7) << 16);
      int slot = (k0 >> 3) ^ (tok & 7);
      *(uint4*)&zs[tok][slot * 8] = make_uint4(w0, w1, w2, w3);
    }
  }
  // ---- stage es: 256 codes (coalesced float4 reads, swizzled b128 writes)
  {
    const int code_ = tid >> 2, q = tid & 3;
#pragma unroll
    for (int co = 0; co < 4; ++co) {
      int code = co * 64 + code_;
      const float* ep = emb + (size_t)(I0 + code) * 64 + q * 16;
      unsigned int w[8];
#pragma unroll
      for (int j = 0; j < 8; ++j)
        w[j] = (unsigned int)f2bf(ep[2 * j]) | ((unsigned int)f2bf(ep[2 * j + 1]) << 16);
      int s0 = (q * 2) ^ (code & 7), s1 = (q * 2 + 1) ^ (code & 7);
      *(uint4*)&es[code][s0 * 8] = make_uint4(w[0], w[1], w[2], w[3]);
      *(uint4*)&es[code][s1 * 8] = make_uint4(w[4], w[5], w[6], w[7]);
    }
  }
  if (tid < 128) tmins[tid] = 0x7F800000u;
  __syncthreads();

  const int l  = tid & 63, w = tid >> 6;
  const int wr = w >> 1, wc = w & 1;
  const int rA = l & 15;
  const int kg = l >> 4;

  f32x4 acc[4][8];
#pragma unroll
  for (int fr = 0; fr < 4; ++fr)
#pragma unroll
    for (int fc = 0; fc < 8; ++fc)
#pragma unroll
      for (int r = 0; r < 4; ++r) acc[fr][fc][r] = 0.0f;

#pragma unroll
  for (int q = 0; q < 2; ++q) {
    bf16x8 af[4], bfv[8];
#pragma unroll
    for (int fr = 0; fr < 4; ++fr) {
      int row  = wr * 64 + fr * 16 + rA;
      int slot = (q * 4 + kg) ^ (row & 7);
      af[fr] = *(const bf16x8*)&zs[row][slot * 8];
    }
#pragma unroll
    for (int fc = 0; fc < 8; ++fc) {
      int crow = wc * 128 + fc * 16 + rA;
      int slot = (q * 4 + kg) ^ (crow & 7);
      bfv[fc] = *(const bf16x8*)&es[crow][slot * 8];
    }
#pragma unroll
    for (int fr = 0; fr < 4; ++fr)
#pragma unroll
      for (int fc = 0; fc < 8; ++fc)
        acc[fr][fc] = __builtin_amdgcn_mfma_f32_16x16x32_bf16(af[fr], bfv[fc], acc[fr][fc], 0, 0, 0);
  }

  // ---- epilogue: per-token min over this block's 256 codes
  float sev[8];
#pragma unroll
  for (int fc = 0; fc < 8; ++fc) sev[fc] = s_e[I0 + wc * 128 + fc * 16 + rA];

#pragma unroll
  for (int fr = 0; fr < 4; ++fr) {
#pragma unroll
    for (int r = 0; r < 4; ++r) {
      int tok = wr * 64 + fr * 16 + kg * 4 + r;   // block-local token
      float szv = s_z[T0 + tok];
      float dm = __uint_as_float(0x7F800000u);
#pragma unroll
      for (int fc = 0; fc < 8; ++fc)
        dm = fminf(dm, (szv + sev[fc]) - 2.0f * acc[fr][fc][r]);
      dm = fminf(dm, __shfl_xor(dm, 1, 64));
      dm = fminf(dm, __shfl_xor(dm, 2, 64));
      dm = fminf(dm, __shfl_xor(dm, 4, 64));
      dm = fminf(dm, __shfl_xor(dm, 8, 64));
      if (rA == 0) atomicMin(&tmins[tok], __float_as_uint(dm));
    }
  }
  __syncthreads();
  if (tid < 128)
    tilemin[(size_t)tslot * TOK + T0 + tid] = tmins[tid];   // coalesced row
}

// ---------------------------------------------------------------------------
// K2: window + compact candidate lists (wave-aggregated; unchanged)
// ---------------------------------------------------------------------------
__global__ __launch_bounds__(256) void k_window(
    const int* __restrict__ mask, const unsigned int* __restrict__ tilemin,
    const unsigned long long* __restrict__ se_min,
    unsigned long long* __restrict__ packed,
    int* __restrict__ cnt, unsigned short* __restrict__ list) {
  const int t = blockIdx.x * 256 + threadIdx.x;
  const int l = threadIdx.x & 63;
  const int mt = mask[t];

  unsigned int tm[NTILE];
  unsigned int mn = 0xFFFFFFFFu;
#pragma unroll
  for (int i = 0; i < NTILE; ++i) {
    tm[i] = tilemin[(size_t)i * TOK + t];
    mn = min(mn, tm[i]);
  }
  const float th = __uint_as_float(mn) + WWIN;

  if (!mt) packed[t] = *se_min;

#pragma unroll
  for (int i = 0; i < NTILE; ++i) {
    bool hit = mt && (__uint_as_float(tm[i]) <= th);
    unsigned long long m = __ballot(hit);
    if (m) {
      int leader = __ffsll((long long)m) - 1;
      int base = 0;
      if (l == leader) base = atomicAdd(&cnt[i], __popcll(m));
      base = __shfl(base, leader, 64);
      if (hit) {
        int rank = __popcll(m & ((1ull << l) - 1ull));
        list[(size_t)i * TOK + base + rank] = (unsigned short)t;
      }
    }
  }
}

// ---------------------------------------------------------------------------
// K3: list-driven exact rescore (unchanged, frozen numerics)
// ---------------------------------------------------------------------------
__global__ __launch_bounds__(256, 2) void k_exact(
    const float* __restrict__ zt, const float* __restrict__ emb,
    const float* __restrict__ s_z, const float* __restrict__ s_e,
    const int* __restrict__ cnt, const unsigned short* __restrict__ list,
    unsigned long long* __restrict__ packed) {
  __shared__ __align__(16) float elT[64][260];   // [k][code]
  const int tile = blockIdx.x;
  const int C0   = tile * 256;
  const int tid  = threadIdx.x, l = tid & 63, w = tid >> 6;

#pragma unroll
  for (int pass = 0; pass < 16; ++pass) {
    int gid = pass * 256 + tid;
    int code = gid >> 4, kq = gid & 15;
    float4 v = *(const float4*)(emb + (size_t)(C0 + code) * 64 + kq * 4);
    elT[kq * 4 + 0][code] = v.x;
    elT[kq * 4 + 1][code] = v.y;
    elT[kq * 4 + 2][code] = v.z;
    elT[kq * 4 + 3][code] = v.w;
  }
  __syncthreads();

  const int n = cnt[tile];
  for (int j = blockIdx.y * 4 + w; j < n; j += 64) {
    int t = (int)list[(size_t)tile * TOK + j];
    t = __builtin_amdgcn_readfirstlane(t);
    const float* zr = zt + (size_t)t * 64;
    float szt = s_z[t];
    float a0 = 0.f, a1 = 0.f, a2 = 0.f, a3 = 0.f;
#pragma unroll 8
    for (int k = 0; k < 64; ++k) {
      float zk = zr[k];
      float4 e4 = *(const float4*)&elT[k][4 * l];
      a0 = fmaf(e4.x, zk, a0);
      a1 = fmaf(e4.y, zk, a1);
      a2 = fmaf(e4.z, zk, a2);
      a3 = fmaf(e4.w, zk, a3);
    }
    unsigned long long best = ~0ull;
    float av[4] = {a0, a1, a2, a3};
#pragma unroll
    for (int q = 0; q < 4; ++q) {
      int code = C0 + 4 * l + q;
      float d = __fsub_rn(__fadd_rn(szt, s_e[code]), __fmul_rn(2.0f, av[q]));
      unsigned int db = __float_as_uint(d);
      db = ((int)db < 0) ? ~db : (db | 0x80000000u);
      unsigned long long p = ((unsigned long long)db << 32) | (unsigned int)code;
      best = (p < best) ? p : best;
    }
#pragma unroll
    for (int off = 1; off < 64; off <<= 1) {
      unsigned long long q = __shfl_xor(best, off, 64);
      best = (q < best) ? q : best;
    }
    if (l == 0) atomicMin(&packed[t], best);
  }
}

// ---------------------------------------------------------------------------
// K4: finalize + FUSED full enc-row write (zeros with inline one-hot).
// Block = 64 rows x 512 thr. Streaming float4 stores, low VGPR -> the 512MB
// write runs at fill-kernel BW (harness fill: 6.5 TB/s at low occupancy).
// zq/loss numerics unchanged (frozen).
// ---------------------------------------------------------------------------
__global__ __launch_bounds__(512) void k_finalize(
    const float* __restrict__ z, const int* __restrict__ mask,
    const float* __restrict__ emb,
    const unsigned long long* __restrict__ packed,
    float* __restrict__ out_zq, float* __restrict__ out_enc,
    float* __restrict__ out_idx,
    int* __restrict__ hist, float* __restrict__ token_loss) {
  __shared__ float part[8][64];
  __shared__ int sidx[64];
  const int T0   = blockIdx.x * 64;
  const int lane = threadIdx.x & 63;
  const int w    = threadIdx.x >> 6;
  const int b    = T0 >> 9;
  const int l0   = T0 & 511;
  const int t    = T0 + lane;

  if (w == 0) sidx[lane] = (int)(unsigned int)(packed[t] & 0xFFFFFFFFu);
  __syncthreads();
  const int idx = sidx[lane];

  const float* zb = z      + (size_t)b * 32768 + l0 + lane;
  float*       qb = out_zq + (size_t)b * 32768 + l0 + lane;

  float sq = 0.0f;
#pragma unroll
  for (int cc = 0; cc < 8; ++cc) {
    int c = w * 8 + cc;
    float zv   = zb[(size_t)c * 512];
    float e    = emb[(size_t)idx * 64 + c];
    float diff = __fsub_rn(e, zv);
    qb[(size_t)c * 512] = __fadd_rn(zv, diff);   // z + (z_q - z), bit-exact STE
    sq = fmaf(diff, diff, sq);
  }
  part[w][lane] = sq;
  __syncthreads();

  if (w == 0) {
    float s = __fadd_rn(
        __fadd_rn(__fadd_rn(part[0][lane], part[1][lane]),
                  __fadd_rn(part[2][lane], part[3][lane])),
        __fadd_rn(__fadd_rn(part[4][lane], part[5][lane]),
                  __fadd_rn(part[6][lane], part[7][lane])));
    token_loss[t] = mask[t] ? s : 0.0f;
    out_idx[t] = (float)idx;
    atomicAdd(&hist[idx], 1);
  }

  // ---- full enc tile write: 64 rows x 8192 floats, one-hot fused inline
  float* encb = out_enc + (size_t)T0 * 8192;
#pragma unroll 4
  for (int it = 0; it < 256; ++it) {
    int id  = it * 512 + threadIdx.x;   // 0..131071 float4 units
    int row = id >> 11;                 // 0..63
    int c4  = id & 2047;                // float4 col
    int ridx = sidx[row];
    float4 v = make_float4(0.f, 0.f, 0.f, 0.f);
    if (c4 == (ridx >> 2)) {            // rare: ~1 wave per row takes this
      v.x = (ridx & 3) == 0 ? 1.0f : 0.0f;
      v.y = (ridx & 3) == 1 ? 1.0f : 0.0f;
      v.z = (ridx & 3) == 2 ? 1.0f : 0.0f;
      v.w = (ridx & 3) == 3 ? 1.0f : 0.0f;
    }
    *(float4*)(encb + (size_t)row * 8192 + c4 * 4) = v;
  }
}

// ---------------------------------------------------------------------------
// K5: scalars — single block, 1024 threads (unchanged)
// ---------------------------------------------------------------------------
__global__ __launch_bounds__(1024) void k_scalars(
    const float* __restrict__ token_loss, const int* __restrict__ mask,
    const int* __restrict__ hist, float* __restrict__ out) {
  __shared__ float sf[1024], sm[1024], sh[1024];
  const int tid = threadIdx.x;
  float s = 0.f, mc = 0.f, h = 0.f;
  for (int i = tid; i < TOK; i += 1024) { s += token_loss[i]; mc += (float)mask[i]; }
  for (int i = tid; i < NE; i += 1024) {
    float pm = (float)hist[i] * (1.0f / 16384.0f);
    h += pm * logf(pm + 1e-10f);
  }
  sf[tid] = s; sm[tid] = mc; sh[tid] = h;
  __syncthreads();
  for (int off = 512; off; off >>= 1) {
    if (tid < off) { sf[tid] += sf[tid + off]; sm[tid] += sm[tid + off]; sh[tid] += sh[tid + off]; }
    __syncthreads();
  }
  if (tid == 0) {
    float denom = sm[0] * 64.0f;
    float el = sf[0] / denom;               // embedding_loss == commitment_loss
    out[0]      = __fadd_rn(el, __fmul_rn(0.25f, el));
    out[O_PERP] = expf(-sh[0]);
  }
}

// ---------------------------------------------------------------------------
extern "C" void kernel_launch(void* const* d_in, const int* in_sizes, int n_in,
                              void* d_out, int out_size, void* d_ws, size_t ws_size,
                              hipStream_t stream) {
  const float* z    = (const float*)d_in[0];
  const int*   mask = (const int*)d_in[1];
  const float* emb  = (const float*)d_in[2];
  float* out = (float*)d_out;
  char*  ws  = (char*)d_ws;

  unsigned long long* packed  = (unsigned long long*)ws;           // 128 KB
  float*              s_z     = (float*)(ws + 131072);             // 64 KB
  float*              s_e     = (float*)(ws + 196608);             // 32 KB
  int*                hist    = (int*)(ws + 229376);               // 32 KB
  float*              token_loss = (float*)(ws + 262144);          // 64 KB
  unsigned long long* se_min  = (unsigned long long*)(ws + 331776);// 8 B
  int*                cnt     = (int*)(ws + 332800);               // 128 B
  unsigned int*       tilemin = (unsigned int*)(ws + 401408);      // 2 MB
  float*              zt      = (float*)(ws + 2498560);            // 4 MB
  unsigned short*     list    = (unsigned short*)(ws + 6692864);   // 1 MB

  k_zero<<<1, 64, 0, stream>>>(se_min, cnt);
  k_init<<<96, 256, 0, stream>>>(z, mask, emb, packed, s_z, s_e, hist, zt, se_min);

  dim3 gm(32, 128, 1);   // x: 256-code tslots, y: 128-token tiles
  k_mfma<<<gm, 256, 0, stream>>>(z, mask, emb, s_z, s_e, tilemin);

  k_window<<<64, 256, 0, stream>>>(mask, tilemin, se_min, packed, cnt, list);

  dim3 ge(32, 16, 1);
  k_exact<<<ge, 256, 0, stream>>>(zt, emb, s_z, s_e, cnt, list, packed);

  k_finalize<<<256, 512, 0, stream>>>(z, mask, emb, packed,
                                      out + O_ZQ, out + O_ENC, out + O_IDX,
                                      hist, token_loss);

  k_scalars<<<1, 1024, 0, stream>>>(token_loss, mask, hist, out);
}

// Round 16
// 364.447 us; speedup vs baseline: 5.9537x; 1.2227x over previous
//
#include <hip/hip_runtime.h>
#include <cstdint>
#include <cstddef>

#define TOK 16384
#define NE  8192
#define NTILE 32          // 256-code tiles
#define WWIN 1.5e-4f      // rescore window (bound ~1.5e-5; validated R9-R15)

// output layout (all float32): loss | z_q(32,64,512) | perp | enc(16384,8192) | idx(16384)
#define O_ZQ   1
#define O_PERP 1048577
#define O_ENC  1048578
#define O_IDX  135266306

typedef short bf16x8 __attribute__((ext_vector_type(8)));
typedef float f32x4  __attribute__((ext_vector_type(4)));

__device__ __forceinline__ unsigned short f2bf(float v) {
  unsigned int u = __float_as_uint(v);
  return (unsigned short)((u + 0x7FFFu + ((u >> 16) & 1u)) >> 16);  // RNE
}

// ---------------------------------------------------------------------------
__global__ void k_zero(unsigned long long* se_min) {
  if (threadIdx.x == 0) *se_min = ~0ull;
}

// ---------------------------------------------------------------------------
// K0: s_z (numpy 8-acc pairwise, masked), zt K-MAJOR (coalesced writes),
// s_e + (se,idx) min, packed=~0   (R10 verbatim)
// ---------------------------------------------------------------------------
__global__ __launch_bounds__(256) void k_init(
    const float* __restrict__ z, const int* __restrict__ mask,
    const float* __restrict__ emb,
    unsigned long long* __restrict__ packed,
    float* __restrict__ s_z, float* __restrict__ s_e,
    int* __restrict__ hist, float* __restrict__ zt,
    unsigned long long* __restrict__ se_min) {
  int g = blockIdx.x * 256 + threadIdx.x;
  if (g < TOK) {
    int t = g, b = t >> 9, l = t & 511;
    const float* zp = z + (size_t)b * 32768 + l;
    const int mt = mask[t];
    float r[8];
#pragma unroll
    for (int j = 0; j < 8; ++j) {
      float v = mt ? zp[(size_t)j * 512] : 0.0f;
      zt[(size_t)j * TOK + t] = v;            // k-major: coalesced
      r[j] = __fmul_rn(v, v);
    }
#pragma unroll
    for (int i = 8; i < 64; i += 8)
#pragma unroll
      for (int j = 0; j < 8; ++j) {
        float v = mt ? zp[(size_t)(i + j) * 512] : 0.0f;
        zt[(size_t)(i + j) * TOK + t] = v;    // k-major: coalesced
        r[j] = __fadd_rn(r[j], __fmul_rn(v, v));
      }
    float s = __fadd_rn(__fadd_rn(__fadd_rn(r[0], r[1]), __fadd_rn(r[2], r[3])),
                        __fadd_rn(__fadd_rn(r[4], r[5]), __fadd_rn(r[6], r[7])));
    s_z[t] = s;
    packed[t] = ~0ull;
  } else if (g < TOK + NE) {
    int i = g - TOK;
    const float* ep = emb + (size_t)i * 64;
    float r[8];
#pragma unroll
    for (int j = 0; j < 8; ++j) { float v = ep[j]; r[j] = __fmul_rn(v, v); }
#pragma unroll
    for (int kk = 8; kk < 64; kk += 8)
#pragma unroll
      for (int j = 0; j < 8; ++j) { float v = ep[kk + j]; r[j] = __fadd_rn(r[j], __fmul_rn(v, v)); }
    float s = __fadd_rn(__fadd_rn(__fadd_rn(r[0], r[1]), __fadd_rn(r[2], r[3])),
                        __fadd_rn(__fadd_rn(r[4], r[5]), __fadd_rn(r[6], r[7])));
    s_e[i] = s;
    hist[i] = 0;
    unsigned long long p = ((unsigned long long)__float_as_uint(s) << 32) | (unsigned int)i;
    atomicMin(se_min, p);
  }
}

// ---------------------------------------------------------------------------
// K1: phase A — bf16 MFMA approx + fused enc fill. NEW: 512 thr (8 waves),
// tile 256 tok x 256 codes -> grid 2048 (8 rounds vs 16), 2 waves/SIMD.
// Per-wave work identical to R10 (64x128, acc[4][8]); numerics unchanged.
// ---------------------------------------------------------------------------
__global__ __launch_bounds__(512, 1) void k_mfma(
    const float* __restrict__ z, const int* __restrict__ mask,
    const float* __restrict__ emb,
    const float* __restrict__ s_z, const float* __restrict__ s_e,
    unsigned int* __restrict__ tilemin, float* __restrict__ enc_out) {
  __shared__ __align__(16) unsigned short zs[256][64];  // [tok][bf16 k], 16B-slot swizzled
  __shared__ __align__(16) unsigned short es[256][64];  // [code][bf16 k]
  __shared__ unsigned int tmins[256];

  const int tid   = threadIdx.x;
  const int tslot = blockIdx.x;        // 0..31 (256-code tile)
  const int I0    = tslot * 256;
  const int T0    = blockIdx.y * 256;  // 256-token tile
  const int b     = T0 >> 9;
  const int l0    = T0 & 511;          // 0 or 256

  // ---- stage zs: 256 tokens (coalesced fp32 reads, swizzled b128 writes)
  {
    const int tok = tid & 255, kh = tid >> 8;          // kh 0..1
    const int mt  = mask[T0 + tok];
    const float* zp = z + (size_t)b * 32768 + l0 + tok;
#pragma unroll
    for (int i = 0; i < 4; ++i) {
      int k0 = kh * 32 + i * 8;
      float v0 = mt ? zp[(size_t)(k0 + 0) * 512] : 0.0f;
      float v1 = mt ? zp[(size_t)(k0 + 1) * 512] : 0.0f;
      float v2 = mt ? zp[(size_t)(k0 + 2) * 512] : 0.0f;
      float v3 = mt ? zp[(size_t)(k0 + 3) * 512] : 0.0f;
      float v4 = mt ? zp[(size_t)(k0 + 4) * 512] : 0.0f;
      float v5 = mt ? zp[(size_t)(k0 + 5) * 512] : 0.0f;
      float v6 = mt ? zp[(size_t)(k0 + 6) * 512] : 0.0f;
      float v7 = mt ? zp[(size_t)(k0 + 7) * 512] : 0.0f;
      unsigned int w0 = (unsigned int)f2bf(v0) | ((unsigned int)f2bf(v1) << 16);
      unsigned int w1 = (unsigned int)f2bf(v2) | ((unsigned int)f2bf(v3) << 16);
      unsigned int w2 = (unsigned int)f2bf(v4) | ((unsigned int)f2bf(v5) << 16);
      unsigned int w3 = (unsigned int)f2bf(v6) | ((unsigned int)f2bf(v7) << 16);
      int slot = (k0 >> 3) ^ (tok & 7);
      *(uint4*)&zs[tok][slot * 8] = make_uint4(w0, w1, w2, w3);
    }
  }
  // ---- stage es: 256 codes (coalesced float4 reads, swizzled b128 writes)
  {
    const int code_ = tid >> 2, q = tid & 3;           // code_ 0..127
#pragma unroll
    for (int co = 0; co < 2; ++co) {
      int code = co * 128 + code_;
      const float* ep = emb + (size_t)(I0 + code) * 64 + q * 16;
      unsigned int w[8];
#pragma unroll
      for (int j = 0; j < 8; ++j)
        w[j] = (unsigned int)f2bf(ep[2 * j]) | ((unsigned int)f2bf(ep[2 * j + 1]) << 16);
      int s0 = (q * 2) ^ (code & 7), s1 = (q * 2 + 1) ^ (code & 7);
      *(uint4*)&es[code][s0 * 8] = make_uint4(w[0], w[1], w[2], w[3]);
      *(uint4*)&es[code][s1 * 8] = make_uint4(w[4], w[5], w[6], w[7]);
    }
  }
  if (tid < 256) tmins[tid] = 0x7F800000u;
  __syncthreads();

  const int l  = tid & 63, w = tid >> 6;   // w 0..7
  const int wr = w >> 1, wc = w & 1;       // wr 0..3 (64-token rows), wc 0..1 (128-code cols)
  const int rA = l & 15;
  const int kg = l >> 4;

  f32x4 acc[4][8];
#pragma unroll
  for (int fr = 0; fr < 4; ++fr)
#pragma unroll
    for (int fc = 0; fc < 8; ++fc)
#pragma unroll
      for (int r = 0; r < 4; ++r) acc[fr][fc][r] = 0.0f;

  float* encb = enc_out + (size_t)T0 * 8192 + I0;

#pragma unroll
  for (int q = 0; q < 2; ++q) {
    bf16x8 af[4], bfv[8];
#pragma unroll
    for (int fr = 0; fr < 4; ++fr) {
      int row  = wr * 64 + fr * 16 + rA;
      int slot = (q * 4 + kg) ^ (row & 7);
      af[fr] = *(const bf16x8*)&zs[row][slot * 8];
    }
#pragma unroll
    for (int fc = 0; fc < 8; ++fc) {
      int crow = wc * 128 + fc * 16 + rA;
      int slot = (q * 4 + kg) ^ (crow & 7);
      bfv[fc] = *(const bf16x8*)&es[crow][slot * 8];
    }
#pragma unroll
    for (int fr = 0; fr < 4; ++fr)
#pragma unroll
      for (int fc = 0; fc < 8; ++fc)
        acc[fr][fc] = __builtin_amdgcn_mfma_f32_16x16x32_bf16(af[fr], bfv[fc], acc[fr][fc], 0, 0, 0);

    // fused enc zero-fill: 256x256 tile = 256 KB; 16 float4/thread/q
#pragma unroll
    for (int it = 0; it < 16; ++it) {
      int id  = q * 8192 + it * 512 + tid;   // 0..16383 float4 units
      int row = id >> 6;                     // 0..255
      int c4  = id & 63;                     // 0..63
      *(float4*)(encb + (size_t)row * 8192 + c4 * 4) = make_float4(0.f, 0.f, 0.f, 0.f);
    }
  }

  // ---- epilogue: per-token min over this block's 256 codes
  float sev[8];
#pragma unroll
  for (int fc = 0; fc < 8; ++fc) sev[fc] = s_e[I0 + wc * 128 + fc * 16 + rA];

#pragma unroll
  for (int fr = 0; fr < 4; ++fr) {
#pragma unroll
    for (int r = 0; r < 4; ++r) {
      int tok = wr * 64 + fr * 16 + kg * 4 + r;   // block-local token 0..255
      float szv = s_z[T0 + tok];
      float dm = __uint_as_float(0x7F800000u);
#pragma unroll
      for (int fc = 0; fc < 8; ++fc)
        dm = fminf(dm, (szv + sev[fc]) - 2.0f * acc[fr][fc][r]);
      dm = fminf(dm, __shfl_xor(dm, 1, 64));
      dm = fminf(dm, __shfl_xor(dm, 2, 64));
      dm = fminf(dm, __shfl_xor(dm, 4, 64));
      dm = fminf(dm, __shfl_xor(dm, 8, 64));
      if (rA == 0) atomicMin(&tmins[tok], __float_as_uint(dm));
    }
  }
  __syncthreads();
  if (tid < 256)
    tilemin[(size_t)tslot * TOK + T0 + tid] = tmins[tid];   // coalesced row
}

// ---------------------------------------------------------------------------
// K2: window — mask0 -> packed = global se-min; mask1 -> thresh (R10 verbatim)
// ---------------------------------------------------------------------------
__global__ __launch_bounds__(256) void k_window(
    const int* __restrict__ mask, const unsigned int* __restrict__ tilemin,
    const unsigned long long* __restrict__ se_min,
    unsigned long long* __restrict__ packed, float* __restrict__ thresh) {
  int t = blockIdx.x * 256 + threadIdx.x;
  if (mask[t]) {
    unsigned int mn = 0xFFFFFFFFu;
#pragma unroll
    for (int i = 0; i < NTILE; ++i)
      mn = min(mn, tilemin[(size_t)i * TOK + t]);   // lane-coalesced
    thresh[t] = __uint_as_float(mn) + WWIN;
  } else {
    packed[t] = *se_min;
    thresh[t] = -1.0f;
  }
}

// ---------------------------------------------------------------------------
// K3: exact rescore (R10 verbatim; frozen numerics; zt k-major)
// ---------------------------------------------------------------------------
__global__ __launch_bounds__(256, 2) void k_exact(
    const float* __restrict__ zt, const float* __restrict__ emb,
    const float* __restrict__ s_z, const float* __restrict__ s_e,
    const unsigned int* __restrict__ tilemin, const float* __restrict__ thresh,
    unsigned long long* __restrict__ packed) {
  __shared__ __align__(16) float elT[64][260];   // [k][code]
  const int tile = blockIdx.x;
  const int C0   = tile * 256;
  const int tid  = threadIdx.x, l = tid & 63, w = tid >> 6;

#pragma unroll
  for (int pass = 0; pass < 16; ++pass) {
    int gid = pass * 256 + tid;
    int code = gid >> 4, kq = gid & 15;
    float4 v = *(const float4*)(emb + (size_t)(C0 + code) * 64 + kq * 4);
    elT[kq * 4 + 0][code] = v.x;
    elT[kq * 4 + 1][code] = v.y;
    elT[kq * 4 + 2][code] = v.z;
    elT[kq * 4 + 3][code] = v.w;
  }
  __syncthreads();

  const int gw   = blockIdx.y * 4 + w;   // 0..31
  const int base = gw * 512;

  for (int s = 0; s < 8; ++s) {
    int tt = base + s * 64 + l;
    float th = thresh[tt];
    unsigned int tm = tilemin[(size_t)tile * TOK + tt];
    unsigned long long bal = __ballot(__uint_as_float(tm) <= th);
    while (bal) {
      int bit = __ffsll((long long)bal) - 1;
      bal &= bal - 1;
      int t = base + s * 64 + bit;                  // uniform
      float szt = s_z[t];
      float a0 = 0.f, a1 = 0.f, a2 = 0.f, a3 = 0.f;
#pragma unroll 8
      for (int k = 0; k < 64; ++k) {
        float zk = zt[(size_t)k * TOK + t];          // wave-uniform scalar
        float4 e4 = *(const float4*)&elT[k][4 * l];  // conflict-free b128
        a0 = fmaf(e4.x, zk, a0);
        a1 = fmaf(e4.y, zk, a1);
        a2 = fmaf(e4.z, zk, a2);
        a3 = fmaf(e4.w, zk, a3);
      }
      unsigned long long best = ~0ull;
      float av[4] = {a0, a1, a2, a3};
#pragma unroll
      for (int q = 0; q < 4; ++q) {
        int code = C0 + 4 * l + q;
        float d = __fsub_rn(__fadd_rn(szt, s_e[code]), __fmul_rn(2.0f, av[q]));
        unsigned int db = __float_as_uint(d);
        db = ((int)db < 0) ? ~db : (db | 0x80000000u);
        unsigned long long p = ((unsigned long long)db << 32) | (unsigned int)code;
        best = (p < best) ? p : best;
      }
#pragma unroll
      for (int off = 1; off < 64; off <<= 1) {
        unsigned long long q = __shfl_xor(best, off, 64);
        best = (q < best) ? q : best;
      }
      if (l == 0) atomicMin(&packed[t], best);
    }
  }
}

// ---------------------------------------------------------------------------
// K4: per-token finalize — coalesced (R10 verbatim)
// ---------------------------------------------------------------------------
__global__ __launch_bounds__(512) void k_finalize(
    const float* __restrict__ z, const int* __restrict__ mask,
    const float* __restrict__ emb,
    const unsigned long long* __restrict__ packed,
    float* __restrict__ out_zq, float* __restrict__ out_enc,
    float* __restrict__ out_idx,
    int* __restrict__ hist, float* __restrict__ token_loss) {
  __shared__ float part[8][64];
  const int T0   = blockIdx.x * 64;
  const int lane = threadIdx.x & 63;
  const int w    = threadIdx.x >> 6;
  const int b    = T0 >> 9;
  const int l0   = T0 & 511;
  const int t    = T0 + lane;

  const int idx = (int)(unsigned int)(packed[t] & 0xFFFFFFFFu);

  const float* zb = z      + (size_t)b * 32768 + l0 + lane;
  float*       qb = out_zq + (size_t)b * 32768 + l0 + lane;

  float sq = 0.0f;
#pragma unroll
  for (int cc = 0; cc < 8; ++cc) {
    int c = w * 8 + cc;
    float zv   = zb[(size_t)c * 512];
    float e    = emb[(size_t)idx * 64 + c];
    float diff = __fsub_rn(e, zv);
    qb[(size_t)c * 512] = __fadd_rn(zv, diff);   // z + (z_q - z), bit-exact STE
    sq = fmaf(diff, diff, sq);
  }
  part[w][lane] = sq;
  __syncthreads();

  if (w == 0) {
    float s = __fadd_rn(
        __fadd_rn(__fadd_rn(part[0][lane], part[1][lane]),
                  __fadd_rn(part[2][lane], part[3][lane])),
        __fadd_rn(__fadd_rn(part[4][lane], part[5][lane]),
                  __fadd_rn(part[6][lane], part[7][lane])));
    token_loss[t] = mask[t] ? s : 0.0f;
    out_idx[t] = (float)idx;
    out_enc[(size_t)t * 8192 + idx] = 1.0f;
    atomicAdd(&hist[idx], 1);
  }
}

// ---------------------------------------------------------------------------
// K5: scalars — single block, 1024 threads (R10 verbatim)
// ---------------------------------------------------------------------------
__global__ __launch_bounds__(1024) void k_scalars(
    const float* __restrict__ token_loss, const int* __restrict__ mask,
    const int* __restrict__ hist, float* __restrict__ out) {
  __shared__ float sf[1024], sm[1024], sh[1024];
  const int tid = threadIdx.x;
  float s = 0.f, mc = 0.f, h = 0.f;
  for (int i = tid; i < TOK; i += 1024) { s += token_loss[i]; mc += (float)mask[i]; }
  for (int i = tid; i < NE; i += 1024) {
    float pm = (float)hist[i] * (1.0f / 16384.0f);
    h += pm * logf(pm + 1e-10f);
  }
  sf[tid] = s; sm[tid] = mc; sh[tid] = h;
  __syncthreads();
  for (int off = 512; off; off >>= 1) {
    if (tid < off) { sf[tid] += sf[tid + off]; sm[tid] += sm[tid + off]; sh[tid] += sh[tid + off]; }
    __syncthreads();
  }
  if (tid == 0) {
    float denom = sm[0] * 64.0f;
    float el = sf[0] / denom;               // embedding_loss == commitment_loss
    out[0]      = __fadd_rn(el, __fmul_rn(0.25f, el));
    out[O_PERP] = expf(-sh[0]);
  }
}

// ---------------------------------------------------------------------------
extern "C" void kernel_launch(void* const* d_in, const int* in_sizes, int n_in,
                              void* d_out, int out_size, void* d_ws, size_t ws_size,
                              hipStream_t stream) {
  const float* z    = (const float*)d_in[0];
  const int*   mask = (const int*)d_in[1];
  const float* emb  = (const float*)d_in[2];
  float* out = (float*)d_out;
  char*  ws  = (char*)d_ws;

  unsigned long long* packed  = (unsigned long long*)ws;           // 128 KB
  float*              s_z     = (float*)(ws + 131072);             // 64 KB
  float*              s_e     = (float*)(ws + 196608);             // 32 KB
  int*                hist    = (int*)(ws + 229376);               // 32 KB
  float*              token_loss = (float*)(ws + 262144);          // 64 KB
  unsigned long long* se_min  = (unsigned long long*)(ws + 331776);// 8 B
  float*              thresh  = (float*)(ws + 335872);             // 64 KB
  unsigned int*       tilemin = (unsigned int*)(ws + 401408);      // 2 MB
  float*              zt      = (float*)(ws + 2498560);            // 4 MB

  k_zero<<<1, 64, 0, stream>>>(se_min);
  k_init<<<96, 256, 0, stream>>>(z, mask, emb, packed, s_z, s_e, hist, zt, se_min);

  dim3 gm(32, 64, 1);   // x: 256-code tslots, y: 256-token tiles
  k_mfma<<<gm, 512, 0, stream>>>(z, mask, emb, s_z, s_e, tilemin, out + O_ENC);

  k_window<<<64, 256, 0, stream>>>(mask, tilemin, se_min, packed, thresh);

  dim3 ge(32, 8, 1);
  k_exact<<<ge, 256, 0, stream>>>(zt, emb, s_z, s_e, tilemin, thresh, packed);

  k_finalize<<<256, 512, 0, stream>>>(z, mask, emb, packed,
                                      out + O_ZQ, out + O_ENC, out + O_IDX,
                                      hist, token_loss);

  k_scalars<<<1, 1024, 0, stream>>>(token_loss, mask, hist, out);
}